// Round 8
// baseline (361.060 us; speedup 1.0000x reference)
//
#include <hip/hip_runtime.h>
#include <math.h>

#define B_    4
#define L_    4092
#define H_    8
#define DM    512
#define WS_   12
#define NW    681
#define NC    682            // 6-row output chunks per (b,h); L = 6*682
#define NC2   341            // chunk PAIRS (682 = 2*341)
#define EPS_  1e-5f
#define Z_ELEMS (B_*L_*DM)   // 8,380,416

typedef unsigned short u16;
typedef __attribute__((ext_vector_type(8))) short short8;
typedef __attribute__((ext_vector_type(4))) float floatx4;

__device__ __forceinline__ u16 f2bf(float f) {
    union { float f; unsigned u; } x; x.f = f;
    unsigned u = x.u;
    return (u16)((u + 0x7FFFu + ((u >> 16) & 1u)) >> 16);
}
__device__ __forceinline__ float bf2f(u16 h) {
    union { unsigned u; float f; } x; x.u = ((unsigned)h) << 16; return x.f;
}
__device__ __forceinline__ float lo16f(unsigned u) {
    union { unsigned x; float f; } a; a.x = u << 16; return a.f;
}
__device__ __forceinline__ float hi16f(unsigned u) {
    union { unsigned x; float f; } a; a.x = u & 0xffff0000u; return a.f;
}
// Dekker-style bf16 split: v = hi + lo + eps, |eps| <= 2^-18 |v|.
__device__ __forceinline__ void pack8_hl(float4 a, float4 b, short8& hi, short8& lo) {
    float v[8] = {a.x, a.y, a.z, a.w, b.x, b.y, b.z, b.w};
    #pragma unroll
    for (int i = 0; i < 8; ++i) {
        u16 h = f2bf(v[i]);
        hi[i] = (short)h;
        lo[i] = (short)f2bf(v[i] - bf2f(h));
    }
}

// ---------------------------------------------------------------------------
// K1: projection GEMM via hi/lo bf16 MFMA, fp32 Q/K outputs (R6-proven
// numerics: absmax 0.03125). R7 lesson: per-wave strided W-pack (16 global
// loads x 64 cache lines + ~800cy f2bf) scales with wave count and ate the
// grid-1024 gain. Fix: W hi/lo pre-packed ONCE per block into LDS
// (coalesced read, 32 f2bf/thread), waves fetch fragments as padded
// ds_read_b128 (row stride 72 u16 -> 2-way = free). Same f2bf per element
// -> bit-identical fragments. Grid (512,3) = R6-proven occupancy.
// MFMA sequence and stores byte-identical to R6.
// ---------------------------------------------------------------------------
__global__ __launch_bounds__(256) void proj_kernel(
    const float* __restrict__ q, const float* __restrict__ k, const float* __restrict__ v,
    const float* __restrict__ Wq, const float* __restrict__ Wk, const float* __restrict__ Wv,
    float* __restrict__ Qf, float* __restrict__ Kf, u16* __restrict__ Vh)
{
    __shared__ u16 Wh16[64 * 72];   // hi plane, rows padded to 72 u16
    __shared__ u16 Wl16[64 * 72];   // lo plane

    const int tensor = blockIdx.y;
    const float* __restrict__ X = (tensor == 0) ? q  : (tensor == 1) ? k  : v;
    const float* __restrict__ W = (tensor == 0) ? Wq : (tensor == 1) ? Wk : Wv;
    float* __restrict__ Yf      = (tensor == 0) ? Qf : Kf;
    const bool isV = (tensor == 2);

    const int t = threadIdx.x, lane = t & 63, wv = t >> 6;
    const int m = lane & 15, q3 = lane >> 4;

    // --- cooperative W hi/lo pre-pack: thread t packs elements t*16..+15 ---
    {
        const int i0 = t * 16;                 // 256 threads x 16 = 4096
        const int r = i0 >> 6, c0 = i0 & 63;   // 16 | c0 -> short8 stores aligned
        const float* wp = W + i0;
        short8 h0, l0, h1, l1;
        pack8_hl(*(const float4*)(wp),     *(const float4*)(wp + 4),  h0, l0);
        pack8_hl(*(const float4*)(wp + 8), *(const float4*)(wp + 12), h1, l1);
        *(short8*)&Wh16[r * 72 + c0]     = h0;
        *(short8*)&Wh16[r * 72 + c0 + 8] = h1;
        *(short8*)&Wl16[r * 72 + c0]     = l0;
        *(short8*)&Wl16[r * 72 + c0 + 8] = l1;
    }
    __syncthreads();

    // W fragments: rows 4m+nt, segment kc*32 + q3*8 (identical values to R6)
    short8 wfh[4][2], wfl[4][2];
    #pragma unroll
    for (int nt = 0; nt < 4; ++nt)
        #pragma unroll
        for (int kc = 0; kc < 2; ++kc) {
            const int off = (4 * m + nt) * 72 + kc * 32 + q3 * 8;
            wfh[nt][kc] = *(const short8*)&Wh16[off];
            wfl[nt][kc] = *(const short8*)&Wl16[off];
        }

    const int waveId = blockIdx.x * 4 + wv;        // 0..2047
    for (int tile = waveId; tile < 8184; tile += 2048) {
        const int rbase = tile * 16;
        const int r = rbase + m;
        const int bh = r / L_;
        const int l = r - bh * L_;
        const int b = bh >> 3, h = bh & 7;
        const float* xp = X + (((size_t)b * L_ + l) * H_ + h) * 64;
        short8 a0h, a0l, a1h, a1l;
        pack8_hl(*(const float4*)(xp + q3 * 8),      *(const float4*)(xp + q3 * 8 + 4),      a0h, a0l);
        pack8_hl(*(const float4*)(xp + 32 + q3 * 8), *(const float4*)(xp + 32 + q3 * 8 + 4), a1h, a1l);

        floatx4 acc[4];
        #pragma unroll
        for (int nt = 0; nt < 4; ++nt) {
            floatx4 c = {0.f, 0.f, 0.f, 0.f};
            c = __builtin_amdgcn_mfma_f32_16x16x32_bf16(a0h, wfh[nt][0], c, 0, 0, 0);
            c = __builtin_amdgcn_mfma_f32_16x16x32_bf16(a1h, wfh[nt][1], c, 0, 0, 0);
            c = __builtin_amdgcn_mfma_f32_16x16x32_bf16(a0h, wfl[nt][0], c, 0, 0, 0);
            c = __builtin_amdgcn_mfma_f32_16x16x32_bf16(a0l, wfh[nt][0], c, 0, 0, 0);
            c = __builtin_amdgcn_mfma_f32_16x16x32_bf16(a1h, wfl[nt][1], c, 0, 0, 0);
            c = __builtin_amdgcn_mfma_f32_16x16x32_bf16(a1l, wfh[nt][1], c, 0, 0, 0);
            acc[nt] = c;
        }
        #pragma unroll
        for (int reg = 0; reg < 4; ++reg) {
            const int row = rbase + q3 * 4 + reg;
            if (!isV) {
                float4 o4;
                o4.x = acc[0][reg]; o4.y = acc[1][reg];
                o4.z = acc[2][reg]; o4.w = acc[3][reg];
                *(float4*)(Yf + (size_t)row * 64 + 4 * m) = o4;
            } else {
                ushort4 o4;
                o4.x = f2bf(acc[0][reg]); o4.y = f2bf(acc[1][reg]);
                o4.z = f2bf(acc[2][reg]); o4.w = f2bf(acc[3][reg]);
                *(ushort4*)(Vh + (size_t)row * 64 + 4 * m) = o4;
            }
        }
    }
}

// ---------------------------------------------------------------------------
// K2a: fused window attention + overlap-add, S=2 super-chunks.
// EXACTLY R6's structure (proven 58.9 µs / absmax 0.03125) with ONE change:
// V staged as raw u16 (copy, no convert) -> LDS 49.2->36.9 KB -> 4 blocks/CU
// (+33% waves hide stage latency). Unpack at use via exact shl/and; PV reads
// are conflict-free (4 distinct addrs/instr + qq-broadcast). NO kt-split /
// wk array / shuffles (R7's spill disaster: hbm 413MB, VGPR pinned 64).
// Weights computed inline per kt, same expressions/order -> z bit-identical.
// ---------------------------------------------------------------------------
__global__ __launch_bounds__(256, 4) void attn_kernel(
    const float* __restrict__ Qf, const float* __restrict__ Kf, const u16* __restrict__ Vh,
    float* __restrict__ attn, float* __restrict__ xout)
{
    __shared__ alignas(16) float Ks[4][24][64];    // 24.6 KB
    __shared__ alignas(16) u16  Vs16[4][24][64];   // 12.3 KB

    const int c2 = blockIdx.x, b = blockIdx.y, hg = blockIdx.z;
    const int t = threadIdx.x, lane = t & 63, w = t >> 6;   // w = head-in-group
    const int h = hg * 4 + w;
    const int qq = lane >> 2, ks = lane & 3;
    const int bh = b * 8 + h;
    const int lbase = c2 * 12 - 6;                 // staged row 0 -> global row lbase

    // --- stage K (fp32) + V (raw u16) for 4 heads x 24 rows, zero-fill OOB ---
    for (int i = t; i < 1536; i += 256) {          // 1536 = 4 heads * 24 rows * 16 seg4
        const int hh  = i / 384;
        const int rem = i - hh * 384;
        const int rr  = rem >> 4;
        const int cc  = (rem & 15) * 4;
        const int l = lbase + rr;
        float4 kf4 = make_float4(0.f, 0.f, 0.f, 0.f);
        ushort4 v4 = {0, 0, 0, 0};
        if (l >= 0 && l < L_) {
            const size_t base = ((size_t)(b * 8 + hg * 4 + hh) * L_ + l) * 64 + cc;
            kf4 = *(const float4*)(Kf + base);
            v4  = *(const ushort4*)(Vh + base);
        }
        *(float4*)&Ks[hh][rr][cc]    = kf4;
        *(ushort4*)&Vs16[hh][rr][cc] = v4;
    }
    __syncthreads();

    #pragma unroll
    for (int j = 0; j < 2; ++j) {
        const int c = c2 * 2 + j;
        const bool hasA = (c < NW), hasB = (c > 0);     // uniform per j-iteration
        const float scale = (hasA && hasB) ? 0.5f : 1.0f;
        const int koff = 6 * j;                          // staged-row offset of this chunk

        // Q segment for global row c*6+qq (zeros on invalid lanes -> s==0, finite)
        float4 qs0, qs1, qs2, qs3;
        const int qmax = hasA ? 12 : 6;
        if (qq < qmax) {
            const float* qp = Qf + ((size_t)bh * L_ + (c * 6 + qq)) * 64 + ks * 16;
            qs0 = *(const float4*)(qp);     qs1 = *(const float4*)(qp + 4);
            qs2 = *(const float4*)(qp + 8); qs3 = *(const float4*)(qp + 12);
        } else {
            qs0 = qs1 = qs2 = qs3 = make_float4(0.f, 0.f, 0.f, 0.f);
        }

        // --- unified dot pass vs the chunk's 18 staged K rows ---
        float s[18];
        #pragma unroll
        for (int kt = 0; kt < 18; ++kt) {
            const float* kp = &Ks[w][koff + kt][ks * 16];
            const float4 k0 = *(const float4*)(kp);
            const float4 k1 = *(const float4*)(kp + 4);
            const float4 k2 = *(const float4*)(kp + 8);
            const float4 k3 = *(const float4*)(kp + 12);
            s[kt] = qs0.x*k0.x + qs0.y*k0.y + qs0.z*k0.z + qs0.w*k0.w
                  + qs1.x*k1.x + qs1.y*k1.y + qs1.z*k1.z + qs1.w*k1.w
                  + qs2.x*k2.x + qs2.y*k2.y + qs2.z*k2.z + qs2.w*k2.w
                  + qs3.x*k3.x + qs3.y*k3.y + qs3.z*k3.z + qs3.w*k3.w;
        }
        #pragma unroll
        for (int kt = 0; kt < 18; ++kt) {
            s[kt] += __shfl_xor(s[kt], 1);
            s[kt] += __shfl_xor(s[kt], 2);
        }

        // --- softmax A: window c, over s[6..17] ---
        float eA[12], invA = 0.f;
        if (hasA) {
            float mxA = s[6];
            #pragma unroll
            for (int jj = 1; jj < 12; ++jj) mxA = fmaxf(mxA, s[6 + jj]);
            float sumA = 0.f;
            #pragma unroll
            for (int jj = 0; jj < 12; ++jj) { eA[jj] = __expf((s[6 + jj] - mxA) * 0.125f); sumA += eA[jj]; }
            invA = 1.0f / sumA;
            if (ks == 0 && qq < 12) {
                float* ao = attn + ((size_t)bh * NW + c) * 144 + qq * 12;
                float4 a0, a1, a2;
                a0.x = eA[0]*invA; a0.y = eA[1]*invA;  a0.z = eA[2]*invA;  a0.w = eA[3]*invA;
                a1.x = eA[4]*invA; a1.y = eA[5]*invA;  a1.z = eA[6]*invA;  a1.w = eA[7]*invA;
                a2.x = eA[8]*invA; a2.y = eA[9]*invA;  a2.z = eA[10]*invA; a2.w = eA[11]*invA;
                *(float4*)(ao)     = a0;
                *(float4*)(ao + 4) = a1;
                *(float4*)(ao + 8) = a2;
            }
        } else {
            #pragma unroll
            for (int jj = 0; jj < 12; ++jj) eA[jj] = 0.f;
        }

        // --- softmax B: window c-1 (this Q row acts as its row qq+6), s[0..11] ---
        float eB[12], invB = 0.f;
        if (hasB) {
            float mxB = s[0];
            #pragma unroll
            for (int jj = 1; jj < 12; ++jj) mxB = fmaxf(mxB, s[jj]);
            float sumB = 0.f;
            #pragma unroll
            for (int jj = 0; jj < 12; ++jj) { eB[jj] = __expf((s[jj] - mxB) * 0.125f); sumB += eB[jj]; }
            invB = 1.0f / sumB;
        } else {
            #pragma unroll
            for (int jj = 0; jj < 12; ++jj) eB[jj] = 0.f;
        }

        // --- fused PV over the chunk's 18 rows, weights inline (R6 order) ---
        if (qq < 6) {
            float4 xo0 = make_float4(0.f,0.f,0.f,0.f), xo1 = xo0, xo2 = xo0, xo3 = xo0;
            #pragma unroll
            for (int kt = 0; kt < 18; ++kt) {
                const float wa = (kt >= 6) ? eA[kt - 6] * invA : 0.f;
                const float wb = (kt < 12) ? eB[kt] * invB : 0.f;
                const float wk = scale * (wa + wb);
                const u16* vp = &Vs16[w][koff + kt][ks * 16];
                const uint4 ua = *(const uint4*)(vp);      // v[0..7]  bf16 pairs
                const uint4 ub = *(const uint4*)(vp + 8);  // v[8..15]
                xo0.x += wk * lo16f(ua.x); xo0.y += wk * hi16f(ua.x);
                xo0.z += wk * lo16f(ua.y); xo0.w += wk * hi16f(ua.y);
                xo1.x += wk * lo16f(ua.z); xo1.y += wk * hi16f(ua.z);
                xo1.z += wk * lo16f(ua.w); xo1.w += wk * hi16f(ua.w);
                xo2.x += wk * lo16f(ub.x); xo2.y += wk * hi16f(ub.x);
                xo2.z += wk * lo16f(ub.y); xo2.w += wk * hi16f(ub.y);
                xo3.x += wk * lo16f(ub.z); xo3.y += wk * hi16f(ub.z);
                xo3.z += wk * lo16f(ub.w); xo3.w += wk * hi16f(ub.w);
            }
            float* xp = xout + ((size_t)b * L_ + (c * 6 + qq)) * DM + h * 64 + ks * 16;
            *(float4*)(xp)      = xo0;
            *(float4*)(xp + 4)  = xo1;
            *(float4*)(xp + 8)  = xo2;
            *(float4*)(xp + 12) = xo3;
        }
    }
}

// ---------------------------------------------------------------------------
// K2b: residual + LayerNorm, streaming (R6-proven version). Wave = row.
// Reads xout (= z buffer) row, adds residual, LN, overwrites the SAME row.
// ---------------------------------------------------------------------------
__global__ __launch_bounds__(512) void ln_kernel(
    const float* __restrict__ qres, const float* __restrict__ gamma,
    const float* __restrict__ beta, float* __restrict__ z)
{
    const int row = blockIdx.x * 8 + (threadIdx.x >> 6);   // 0..16367
    const int lane = threadIdx.x & 63;
    const int cc = lane * 8;

    float* xp = z + (size_t)row * DM + cc;
    float4 xa = *(const float4*)(xp);
    float4 xb = *(const float4*)(xp + 4);
    const float* qr = qres + (size_t)row * DM + cc;
    const float4 ra  = *(const float4*)qr;
    const float4 rb2 = *(const float4*)(qr + 4);
    xa.x += ra.x;  xa.y += ra.y;  xa.z += ra.z;  xa.w += ra.w;
    xb.x += rb2.x; xb.y += rb2.y; xb.z += rb2.z; xb.w += rb2.w;

    float s1 = xa.x + xa.y + xa.z + xa.w + xb.x + xb.y + xb.z + xb.w;
    float s2 = xa.x*xa.x + xa.y*xa.y + xa.z*xa.z + xa.w*xa.w
             + xb.x*xb.x + xb.y*xb.y + xb.z*xb.z + xb.w*xb.w;
    #pragma unroll
    for (int off = 1; off < 64; off <<= 1) {
        s1 += __shfl_xor(s1, off, 64);
        s2 += __shfl_xor(s2, off, 64);
    }
    const float mu  = s1 * (1.0f / 512.0f);
    const float var = s2 * (1.0f / 512.0f) - mu * mu;
    const float inv = 1.0f / sqrtf(var + EPS_);

    const float4 ga = *(const float4*)(gamma + cc);
    const float4 gb = *(const float4*)(gamma + cc + 4);
    const float4 ba = *(const float4*)(beta + cc);
    const float4 bb = *(const float4*)(beta + cc + 4);
    float4 oa, ob;
    oa.x = (xa.x - mu) * inv * ga.x + ba.x;
    oa.y = (xa.y - mu) * inv * ga.y + ba.y;
    oa.z = (xa.z - mu) * inv * ga.z + ba.z;
    oa.w = (xa.w - mu) * inv * ga.w + ba.w;
    ob.x = (xb.x - mu) * inv * gb.x + bb.x;
    ob.y = (xb.y - mu) * inv * gb.y + bb.y;
    ob.z = (xb.z - mu) * inv * gb.z + bb.z;
    ob.w = (xb.w - mu) * inv * gb.w + bb.w;
    *(float4*)(xp)     = oa;
    *(float4*)(xp + 4) = ob;
}

extern "C" void kernel_launch(void* const* d_in, const int* in_sizes, int n_in,
                              void* d_out, int out_size, void* d_ws, size_t ws_size,
                              hipStream_t stream) {
    const float* q     = (const float*)d_in[0];
    const float* k     = (const float*)d_in[1];
    const float* v     = (const float*)d_in[2];
    const float* Wq    = (const float*)d_in[3];
    const float* Wk    = (const float*)d_in[4];
    const float* Wv    = (const float*)d_in[5];
    const float* gamma = (const float*)d_in[6];
    const float* beta  = (const float*)d_in[7];

    float* z    = (float*)d_out;
    float* attn = (float*)d_out + Z_ELEMS;

    // Workspace: Qf fp32 (33.5 MB) + Kf fp32 (33.5 MB) + Vh bf16 (16.8 MB)
    const size_t plane = (size_t)B_ * H_ * L_ * 64;   // 8,380,416 elements
    float* Qf = (float*)d_ws;
    float* Kf = Qf + plane;
    u16*  Vh  = (u16*)(Kf + plane);

    proj_kernel<<<dim3(512, 3, 1), 256, 0, stream>>>(q, k, v, Wq, Wk, Wv, Qf, Kf, Vh);
    attn_kernel<<<dim3(NC2, B_, 2), 256, 0, stream>>>(Qf, Kf, Vh, attn, z);
    ln_kernel<<<dim3(2046, 1, 1), 512, 0, stream>>>(q, gamma, beta, z);
}

// Round 9
// 298.139 us; speedup vs baseline: 1.2110x; 1.2110x over previous
//
#include <hip/hip_runtime.h>
#include <math.h>

#define B_    4
#define L_    4092
#define H_    8
#define DM    512
#define WS_   12
#define NW    681
#define NC    682            // 6-row output chunks per (b,h); L = 6*682
#define NC2   341            // chunk PAIRS (682 = 2*341)
#define EPS_  1e-5f
#define Z_ELEMS (B_*L_*DM)   // 8,380,416

typedef unsigned short u16;
typedef __attribute__((ext_vector_type(8))) short short8;
typedef __attribute__((ext_vector_type(4))) float floatx4;

__device__ __forceinline__ u16 f2bf(float f) {
    union { float f; unsigned u; } x; x.f = f;
    unsigned u = x.u;
    return (u16)((u + 0x7FFFu + ((u >> 16) & 1u)) >> 16);
}
__device__ __forceinline__ float bf2f(u16 h) {
    union { unsigned u; float f; } x; x.u = ((unsigned)h) << 16; return x.f;
}
__device__ __forceinline__ float lo16f(unsigned u) {
    union { unsigned x; float f; } a; a.x = u << 16; return a.f;
}
__device__ __forceinline__ float hi16f(unsigned u) {
    union { unsigned x; float f; } a; a.x = u & 0xffff0000u; return a.f;
}
// Dekker-style bf16 split: v = hi + lo + eps, |eps| <= 2^-18 |v|.
__device__ __forceinline__ void pack8_hl(float4 a, float4 b, short8& hi, short8& lo) {
    float v[8] = {a.x, a.y, a.z, a.w, b.x, b.y, b.z, b.w};
    #pragma unroll
    for (int i = 0; i < 8; ++i) {
        u16 h = f2bf(v[i]);
        hi[i] = (short)h;
        lo[i] = (short)f2bf(v[i] - bf2f(h));
    }
}

// ---------------------------------------------------------------------------
// K1: projection GEMM via hi/lo bf16 MFMA, fp32 Q/K outputs (absmax-proven
// 0.03125 since R6). W hi/lo pre-packed ONCE per block into LDS (coalesced
// read, 16 f2bf/thread) -> the W cost is per-BLOCK, so a bigger grid is now
// cheap (R7's per-wave W storm is gone). Grid (1024,3): 12 blocks/CU, 2
// tiles/wave -> doubles latency hiding toward the 29 µs memory floor.
// MFMA sequence and stores byte-identical to R6/R8.
// ---------------------------------------------------------------------------
__global__ __launch_bounds__(256) void proj_kernel(
    const float* __restrict__ q, const float* __restrict__ k, const float* __restrict__ v,
    const float* __restrict__ Wq, const float* __restrict__ Wk, const float* __restrict__ Wv,
    float* __restrict__ Qf, float* __restrict__ Kf, u16* __restrict__ Vh)
{
    __shared__ u16 Wh16[64 * 72];   // hi plane, rows padded to 72 u16
    __shared__ u16 Wl16[64 * 72];   // lo plane

    const int tensor = blockIdx.y;
    const float* __restrict__ X = (tensor == 0) ? q  : (tensor == 1) ? k  : v;
    const float* __restrict__ W = (tensor == 0) ? Wq : (tensor == 1) ? Wk : Wv;
    float* __restrict__ Yf      = (tensor == 0) ? Qf : Kf;
    const bool isV = (tensor == 2);

    const int t = threadIdx.x, lane = t & 63, wv = t >> 6;
    const int m = lane & 15, q3 = lane >> 4;

    // --- cooperative W hi/lo pre-pack: thread t packs elements t*16..+15 ---
    {
        const int i0 = t * 16;                 // 256 threads x 16 = 4096
        const int r = i0 >> 6, c0 = i0 & 63;   // 16 | c0 -> short8 stores aligned
        const float* wp = W + i0;
        short8 h0, l0, h1, l1;
        pack8_hl(*(const float4*)(wp),     *(const float4*)(wp + 4),  h0, l0);
        pack8_hl(*(const float4*)(wp + 8), *(const float4*)(wp + 12), h1, l1);
        *(short8*)&Wh16[r * 72 + c0]     = h0;
        *(short8*)&Wh16[r * 72 + c0 + 8] = h1;
        *(short8*)&Wl16[r * 72 + c0]     = l0;
        *(short8*)&Wl16[r * 72 + c0 + 8] = l1;
    }
    __syncthreads();

    // W fragments: rows 4m+nt, segment kc*32 + q3*8 (identical values to R6)
    short8 wfh[4][2], wfl[4][2];
    #pragma unroll
    for (int nt = 0; nt < 4; ++nt)
        #pragma unroll
        for (int kc = 0; kc < 2; ++kc) {
            const int off = (4 * m + nt) * 72 + kc * 32 + q3 * 8;
            wfh[nt][kc] = *(const short8*)&Wh16[off];
            wfl[nt][kc] = *(const short8*)&Wl16[off];
        }

    const int waveId = blockIdx.x * 4 + wv;        // 0..4095
    for (int tile = waveId; tile < 8184; tile += 4096) {
        const int rbase = tile * 16;
        const int r = rbase + m;
        const int bh = r / L_;
        const int l = r - bh * L_;
        const int b = bh >> 3, h = bh & 7;
        const float* xp = X + (((size_t)b * L_ + l) * H_ + h) * 64;
        short8 a0h, a0l, a1h, a1l;
        pack8_hl(*(const float4*)(xp + q3 * 8),      *(const float4*)(xp + q3 * 8 + 4),      a0h, a0l);
        pack8_hl(*(const float4*)(xp + 32 + q3 * 8), *(const float4*)(xp + 32 + q3 * 8 + 4), a1h, a1l);

        floatx4 acc[4];
        #pragma unroll
        for (int nt = 0; nt < 4; ++nt) {
            floatx4 c = {0.f, 0.f, 0.f, 0.f};
            c = __builtin_amdgcn_mfma_f32_16x16x32_bf16(a0h, wfh[nt][0], c, 0, 0, 0);
            c = __builtin_amdgcn_mfma_f32_16x16x32_bf16(a1h, wfh[nt][1], c, 0, 0, 0);
            c = __builtin_amdgcn_mfma_f32_16x16x32_bf16(a0h, wfl[nt][0], c, 0, 0, 0);
            c = __builtin_amdgcn_mfma_f32_16x16x32_bf16(a0l, wfh[nt][0], c, 0, 0, 0);
            c = __builtin_amdgcn_mfma_f32_16x16x32_bf16(a1h, wfl[nt][1], c, 0, 0, 0);
            c = __builtin_amdgcn_mfma_f32_16x16x32_bf16(a1l, wfh[nt][1], c, 0, 0, 0);
            acc[nt] = c;
        }
        #pragma unroll
        for (int reg = 0; reg < 4; ++reg) {
            const int row = rbase + q3 * 4 + reg;
            if (!isV) {
                float4 o4;
                o4.x = acc[0][reg]; o4.y = acc[1][reg];
                o4.z = acc[2][reg]; o4.w = acc[3][reg];
                *(float4*)(Yf + (size_t)row * 64 + 4 * m) = o4;
            } else {
                ushort4 o4;
                o4.x = f2bf(acc[0][reg]); o4.y = f2bf(acc[1][reg]);
                o4.z = f2bf(acc[2][reg]); o4.w = f2bf(acc[3][reg]);
                *(ushort4*)(Vh + (size_t)row * 64 + 4 * m) = o4;
            }
        }
    }
}

// ---------------------------------------------------------------------------
// K2a: fused window attention + overlap-add, S=2 super-chunks.
// R8 post-mortem: __launch_bounds__(256,4) pinned VGPR to 64 < ~76 live ->
// scratch spill (548 MB HBM round-trips, 197 µs). THE fix is (256,3): cap
// 170, natural VGPR ~76-84, still 4 waves/SIMD (VGPR<=128) and 4 blocks/CU
// by LDS (36.9 KB: K fp32 + V raw u16). Same mechanism explains R7.
// All arithmetic identical to R6 -> z bit-identical (absmax 0.03125).
// ---------------------------------------------------------------------------
__global__ __launch_bounds__(256, 3) void attn_kernel(
    const float* __restrict__ Qf, const float* __restrict__ Kf, const u16* __restrict__ Vh,
    float* __restrict__ attn, float* __restrict__ xout)
{
    __shared__ alignas(16) float Ks[4][24][64];    // 24.6 KB
    __shared__ alignas(16) u16  Vs16[4][24][64];   // 12.3 KB

    const int c2 = blockIdx.x, b = blockIdx.y, hg = blockIdx.z;
    const int t = threadIdx.x, lane = t & 63, w = t >> 6;   // w = head-in-group
    const int h = hg * 4 + w;
    const int qq = lane >> 2, ks = lane & 3;
    const int bh = b * 8 + h;
    const int lbase = c2 * 12 - 6;                 // staged row 0 -> global row lbase

    // --- stage K (fp32) + V (raw u16) for 4 heads x 24 rows, zero-fill OOB ---
    for (int i = t; i < 1536; i += 256) {          // 1536 = 4 heads * 24 rows * 16 seg4
        const int hh  = i / 384;
        const int rem = i - hh * 384;
        const int rr  = rem >> 4;
        const int cc  = (rem & 15) * 4;
        const int l = lbase + rr;
        float4 kf4 = make_float4(0.f, 0.f, 0.f, 0.f);
        ushort4 v4 = {0, 0, 0, 0};
        if (l >= 0 && l < L_) {
            const size_t base = ((size_t)(b * 8 + hg * 4 + hh) * L_ + l) * 64 + cc;
            kf4 = *(const float4*)(Kf + base);
            v4  = *(const ushort4*)(Vh + base);
        }
        *(float4*)&Ks[hh][rr][cc]    = kf4;
        *(ushort4*)&Vs16[hh][rr][cc] = v4;
    }
    __syncthreads();

    #pragma unroll
    for (int j = 0; j < 2; ++j) {
        const int c = c2 * 2 + j;
        const bool hasA = (c < NW), hasB = (c > 0);     // uniform per j-iteration
        const float scale = (hasA && hasB) ? 0.5f : 1.0f;
        const int koff = 6 * j;                          // staged-row offset of this chunk

        // Q segment for global row c*6+qq (zeros on invalid lanes -> s==0, finite)
        float4 qs0, qs1, qs2, qs3;
        const int qmax = hasA ? 12 : 6;
        if (qq < qmax) {
            const float* qp = Qf + ((size_t)bh * L_ + (c * 6 + qq)) * 64 + ks * 16;
            qs0 = *(const float4*)(qp);     qs1 = *(const float4*)(qp + 4);
            qs2 = *(const float4*)(qp + 8); qs3 = *(const float4*)(qp + 12);
        } else {
            qs0 = qs1 = qs2 = qs3 = make_float4(0.f, 0.f, 0.f, 0.f);
        }

        // --- unified dot pass vs the chunk's 18 staged K rows ---
        float s[18];
        #pragma unroll
        for (int kt = 0; kt < 18; ++kt) {
            const float* kp = &Ks[w][koff + kt][ks * 16];
            const float4 k0 = *(const float4*)(kp);
            const float4 k1 = *(const float4*)(kp + 4);
            const float4 k2 = *(const float4*)(kp + 8);
            const float4 k3 = *(const float4*)(kp + 12);
            s[kt] = qs0.x*k0.x + qs0.y*k0.y + qs0.z*k0.z + qs0.w*k0.w
                  + qs1.x*k1.x + qs1.y*k1.y + qs1.z*k1.z + qs1.w*k1.w
                  + qs2.x*k2.x + qs2.y*k2.y + qs2.z*k2.z + qs2.w*k2.w
                  + qs3.x*k3.x + qs3.y*k3.y + qs3.z*k3.z + qs3.w*k3.w;
        }
        #pragma unroll
        for (int kt = 0; kt < 18; ++kt) {
            s[kt] += __shfl_xor(s[kt], 1);
            s[kt] += __shfl_xor(s[kt], 2);
        }

        // --- softmax A: window c, over s[6..17] ---
        float eA[12], invA = 0.f;
        if (hasA) {
            float mxA = s[6];
            #pragma unroll
            for (int jj = 1; jj < 12; ++jj) mxA = fmaxf(mxA, s[6 + jj]);
            float sumA = 0.f;
            #pragma unroll
            for (int jj = 0; jj < 12; ++jj) { eA[jj] = __expf((s[6 + jj] - mxA) * 0.125f); sumA += eA[jj]; }
            invA = 1.0f / sumA;
            if (ks == 0 && qq < 12) {
                float* ao = attn + ((size_t)bh * NW + c) * 144 + qq * 12;
                float4 a0, a1, a2;
                a0.x = eA[0]*invA; a0.y = eA[1]*invA;  a0.z = eA[2]*invA;  a0.w = eA[3]*invA;
                a1.x = eA[4]*invA; a1.y = eA[5]*invA;  a1.z = eA[6]*invA;  a1.w = eA[7]*invA;
                a2.x = eA[8]*invA; a2.y = eA[9]*invA;  a2.z = eA[10]*invA; a2.w = eA[11]*invA;
                *(float4*)(ao)     = a0;
                *(float4*)(ao + 4) = a1;
                *(float4*)(ao + 8) = a2;
            }
        } else {
            #pragma unroll
            for (int jj = 0; jj < 12; ++jj) eA[jj] = 0.f;
        }

        // --- softmax B: window c-1 (this Q row acts as its row qq+6), s[0..11] ---
        float eB[12], invB = 0.f;
        if (hasB) {
            float mxB = s[0];
            #pragma unroll
            for (int jj = 1; jj < 12; ++jj) mxB = fmaxf(mxB, s[jj]);
            float sumB = 0.f;
            #pragma unroll
            for (int jj = 0; jj < 12; ++jj) { eB[jj] = __expf((s[jj] - mxB) * 0.125f); sumB += eB[jj]; }
            invB = 1.0f / sumB;
        } else {
            #pragma unroll
            for (int jj = 0; jj < 12; ++jj) eB[jj] = 0.f;
        }

        // --- fused PV over the chunk's 18 rows, weights inline (R6 order) ---
        if (qq < 6) {
            float4 xo0 = make_float4(0.f,0.f,0.f,0.f), xo1 = xo0, xo2 = xo0, xo3 = xo0;
            #pragma unroll
            for (int kt = 0; kt < 18; ++kt) {
                const float wa = (kt >= 6) ? eA[kt - 6] * invA : 0.f;
                const float wb = (kt < 12) ? eB[kt] * invB : 0.f;
                const float wk = scale * (wa + wb);
                const u16* vp = &Vs16[w][koff + kt][ks * 16];
                const uint4 ua = *(const uint4*)(vp);      // v[0..7]  bf16 pairs
                const uint4 ub = *(const uint4*)(vp + 8);  // v[8..15]
                xo0.x += wk * lo16f(ua.x); xo0.y += wk * hi16f(ua.x);
                xo0.z += wk * lo16f(ua.y); xo0.w += wk * hi16f(ua.y);
                xo1.x += wk * lo16f(ua.z); xo1.y += wk * hi16f(ua.z);
                xo1.z += wk * lo16f(ua.w); xo1.w += wk * hi16f(ua.w);
                xo2.x += wk * lo16f(ub.x); xo2.y += wk * hi16f(ub.x);
                xo2.z += wk * lo16f(ub.y); xo2.w += wk * hi16f(ub.y);
                xo3.x += wk * lo16f(ub.z); xo3.y += wk * hi16f(ub.z);
                xo3.z += wk * lo16f(ub.w); xo3.w += wk * hi16f(ub.w);
            }
            float* xp = xout + ((size_t)b * L_ + (c * 6 + qq)) * DM + h * 64 + ks * 16;
            *(float4*)(xp)      = xo0;
            *(float4*)(xp + 4)  = xo1;
            *(float4*)(xp + 8)  = xo2;
            *(float4*)(xp + 12) = xo3;
        }
    }
}

// ---------------------------------------------------------------------------
// K2b: residual + LayerNorm, streaming (R6-proven version). Wave = row.
// Reads xout (= z buffer) row, adds residual, LN, overwrites the SAME row.
// ---------------------------------------------------------------------------
__global__ __launch_bounds__(512) void ln_kernel(
    const float* __restrict__ qres, const float* __restrict__ gamma,
    const float* __restrict__ beta, float* __restrict__ z)
{
    const int row = blockIdx.x * 8 + (threadIdx.x >> 6);   // 0..16367
    const int lane = threadIdx.x & 63;
    const int cc = lane * 8;

    float* xp = z + (size_t)row * DM + cc;
    float4 xa = *(const float4*)(xp);
    float4 xb = *(const float4*)(xp + 4);
    const float* qr = qres + (size_t)row * DM + cc;
    const float4 ra  = *(const float4*)qr;
    const float4 rb2 = *(const float4*)(qr + 4);
    xa.x += ra.x;  xa.y += ra.y;  xa.z += ra.z;  xa.w += ra.w;
    xb.x += rb2.x; xb.y += rb2.y; xb.z += rb2.z; xb.w += rb2.w;

    float s1 = xa.x + xa.y + xa.z + xa.w + xb.x + xb.y + xb.z + xb.w;
    float s2 = xa.x*xa.x + xa.y*xa.y + xa.z*xa.z + xa.w*xa.w
             + xb.x*xb.x + xb.y*xb.y + xb.z*xb.z + xb.w*xb.w;
    #pragma unroll
    for (int off = 1; off < 64; off <<= 1) {
        s1 += __shfl_xor(s1, off, 64);
        s2 += __shfl_xor(s2, off, 64);
    }
    const float mu  = s1 * (1.0f / 512.0f);
    const float var = s2 * (1.0f / 512.0f) - mu * mu;
    const float inv = 1.0f / sqrtf(var + EPS_);

    const float4 ga = *(const float4*)(gamma + cc);
    const float4 gb = *(const float4*)(gamma + cc + 4);
    const float4 ba = *(const float4*)(beta + cc);
    const float4 bb = *(const float4*)(beta + cc + 4);
    float4 oa, ob;
    oa.x = (xa.x - mu) * inv * ga.x + ba.x;
    oa.y = (xa.y - mu) * inv * ga.y + ba.y;
    oa.z = (xa.z - mu) * inv * ga.z + ba.z;
    oa.w = (xa.w - mu) * inv * ga.w + ba.w;
    ob.x = (xb.x - mu) * inv * gb.x + bb.x;
    ob.y = (xb.y - mu) * inv * gb.y + bb.y;
    ob.z = (xb.z - mu) * inv * gb.z + bb.z;
    ob.w = (xb.w - mu) * inv * gb.w + bb.w;
    *(float4*)(xp)     = oa;
    *(float4*)(xp + 4) = ob;
}

extern "C" void kernel_launch(void* const* d_in, const int* in_sizes, int n_in,
                              void* d_out, int out_size, void* d_ws, size_t ws_size,
                              hipStream_t stream) {
    const float* q     = (const float*)d_in[0];
    const float* k     = (const float*)d_in[1];
    const float* v     = (const float*)d_in[2];
    const float* Wq    = (const float*)d_in[3];
    const float* Wk    = (const float*)d_in[4];
    const float* Wv    = (const float*)d_in[5];
    const float* gamma = (const float*)d_in[6];
    const float* beta  = (const float*)d_in[7];

    float* z    = (float*)d_out;
    float* attn = (float*)d_out + Z_ELEMS;

    // Workspace: Qf fp32 (33.5 MB) + Kf fp32 (33.5 MB) + Vh bf16 (16.8 MB)
    const size_t plane = (size_t)B_ * H_ * L_ * 64;   // 8,380,416 elements
    float* Qf = (float*)d_ws;
    float* Kf = Qf + plane;
    u16*  Vh  = (u16*)(Kf + plane);

    proj_kernel<<<dim3(1024, 3, 1), 256, 0, stream>>>(q, k, v, Wq, Wk, Wv, Qf, Kf, Vh);
    attn_kernel<<<dim3(NC2, B_, 2), 256, 0, stream>>>(Qf, Kf, Vh, attn, z);
    ln_kernel<<<dim3(2046, 1, 1), 512, 0, stream>>>(q, gamma, beta, z);
}

// Round 10
// 219.473 us; speedup vs baseline: 1.6451x; 1.3584x over previous
//
#include <hip/hip_runtime.h>
#include <math.h>

#define B_    4
#define L_    4092
#define H_    8
#define DM    512
#define WS_   12
#define NW    681
#define NC    682            // 6-row output chunks per (b,h); L = 6*682
#define NC2   341            // chunk PAIRS (682 = 2*341)
#define EPS_  1e-5f
#define Z_ELEMS (B_*L_*DM)   // 8,380,416

typedef unsigned short u16;
typedef __attribute__((ext_vector_type(8))) short short8;
typedef __attribute__((ext_vector_type(4))) float floatx4;

__device__ __forceinline__ u16 f2bf(float f) {
    union { float f; unsigned u; } x; x.f = f;
    unsigned u = x.u;
    return (u16)((u + 0x7FFFu + ((u >> 16) & 1u)) >> 16);
}
__device__ __forceinline__ float bf2f(u16 h) {
    union { unsigned u; float f; } x; x.u = ((unsigned)h) << 16; return x.f;
}
// Dekker-style bf16 split: v = hi + lo + eps, |eps| <= 2^-18 |v|.
__device__ __forceinline__ void pack8_hl(float4 a, float4 b, short8& hi, short8& lo) {
    float v[8] = {a.x, a.y, a.z, a.w, b.x, b.y, b.z, b.w};
    #pragma unroll
    for (int i = 0; i < 8; ++i) {
        u16 h = f2bf(v[i]);
        hi[i] = (short)h;
        lo[i] = (short)f2bf(v[i] - bf2f(h));
    }
}

// ---------------------------------------------------------------------------
// K1: projection GEMM via hi/lo bf16 MFMA, fp32 Q/K outputs (absmax-proven
// 0.03125 since R6). W hi/lo pre-packed ONCE per block into LDS (coalesced
// read, 16 f2bf/thread); grid (1024,3) = 12 blocks/CU for latency hiding.
// Kept from R9 (timing algebra: proj_R9 ~ proj_R6; this variant is
// mechanistically sounder). MFMA sequence/stores byte-identical to R6.
// ---------------------------------------------------------------------------
__global__ __launch_bounds__(256) void proj_kernel(
    const float* __restrict__ q, const float* __restrict__ k, const float* __restrict__ v,
    const float* __restrict__ Wq, const float* __restrict__ Wk, const float* __restrict__ Wv,
    float* __restrict__ Qf, float* __restrict__ Kf, u16* __restrict__ Vh)
{
    __shared__ u16 Wh16[64 * 72];   // hi plane, rows padded to 72 u16
    __shared__ u16 Wl16[64 * 72];   // lo plane

    const int tensor = blockIdx.y;
    const float* __restrict__ X = (tensor == 0) ? q  : (tensor == 1) ? k  : v;
    const float* __restrict__ W = (tensor == 0) ? Wq : (tensor == 1) ? Wk : Wv;
    float* __restrict__ Yf      = (tensor == 0) ? Qf : Kf;
    const bool isV = (tensor == 2);

    const int t = threadIdx.x, lane = t & 63, wv = t >> 6;
    const int m = lane & 15, q3 = lane >> 4;

    // --- cooperative W hi/lo pre-pack: thread t packs elements t*16..+15 ---
    {
        const int i0 = t * 16;                 // 256 threads x 16 = 4096
        const int r = i0 >> 6, c0 = i0 & 63;
        const float* wp = W + i0;
        short8 h0, l0, h1, l1;
        pack8_hl(*(const float4*)(wp),     *(const float4*)(wp + 4),  h0, l0);
        pack8_hl(*(const float4*)(wp + 8), *(const float4*)(wp + 12), h1, l1);
        *(short8*)&Wh16[r * 72 + c0]     = h0;
        *(short8*)&Wh16[r * 72 + c0 + 8] = h1;
        *(short8*)&Wl16[r * 72 + c0]     = l0;
        *(short8*)&Wl16[r * 72 + c0 + 8] = l1;
    }
    __syncthreads();

    // W fragments: rows 4m+nt, segment kc*32 + q3*8 (identical values to R6)
    short8 wfh[4][2], wfl[4][2];
    #pragma unroll
    for (int nt = 0; nt < 4; ++nt)
        #pragma unroll
        for (int kc = 0; kc < 2; ++kc) {
            const int off = (4 * m + nt) * 72 + kc * 32 + q3 * 8;
            wfh[nt][kc] = *(const short8*)&Wh16[off];
            wfl[nt][kc] = *(const short8*)&Wl16[off];
        }

    const int waveId = blockIdx.x * 4 + wv;        // 0..4095
    for (int tile = waveId; tile < 8184; tile += 4096) {
        const int rbase = tile * 16;
        const int r = rbase + m;
        const int bh = r / L_;
        const int l = r - bh * L_;
        const int b = bh >> 3, h = bh & 7;
        const float* xp = X + (((size_t)b * L_ + l) * H_ + h) * 64;
        short8 a0h, a0l, a1h, a1l;
        pack8_hl(*(const float4*)(xp + q3 * 8),      *(const float4*)(xp + q3 * 8 + 4),      a0h, a0l);
        pack8_hl(*(const float4*)(xp + 32 + q3 * 8), *(const float4*)(xp + 32 + q3 * 8 + 4), a1h, a1l);

        floatx4 acc[4];
        #pragma unroll
        for (int nt = 0; nt < 4; ++nt) {
            floatx4 c = {0.f, 0.f, 0.f, 0.f};
            c = __builtin_amdgcn_mfma_f32_16x16x32_bf16(a0h, wfh[nt][0], c, 0, 0, 0);
            c = __builtin_amdgcn_mfma_f32_16x16x32_bf16(a1h, wfh[nt][1], c, 0, 0, 0);
            c = __builtin_amdgcn_mfma_f32_16x16x32_bf16(a0h, wfl[nt][0], c, 0, 0, 0);
            c = __builtin_amdgcn_mfma_f32_16x16x32_bf16(a0l, wfh[nt][0], c, 0, 0, 0);
            c = __builtin_amdgcn_mfma_f32_16x16x32_bf16(a1h, wfl[nt][1], c, 0, 0, 0);
            c = __builtin_amdgcn_mfma_f32_16x16x32_bf16(a1l, wfh[nt][1], c, 0, 0, 0);
            acc[nt] = c;
        }
        #pragma unroll
        for (int reg = 0; reg < 4; ++reg) {
            const int row = rbase + q3 * 4 + reg;
            if (!isV) {
                float4 o4;
                o4.x = acc[0][reg]; o4.y = acc[1][reg];
                o4.z = acc[2][reg]; o4.w = acc[3][reg];
                *(float4*)(Yf + (size_t)row * 64 + 4 * m) = o4;
            } else {
                ushort4 o4;
                o4.x = f2bf(acc[0][reg]); o4.y = f2bf(acc[1][reg]);
                o4.z = f2bf(acc[2][reg]); o4.w = f2bf(acc[3][reg]);
                *(ushort4*)(Vh + (size_t)row * 64 + 4 * m) = o4;
            }
        }
    }
}

// ---------------------------------------------------------------------------
// K2a: fused window attention + overlap-add, S=2 super-chunks.
// BYTE-EXACT R6 REVERT (proven 58.9 µs, VGPR 76, hbm 1.2e8, absmax 0.03125).
// R7/R8/R9 all modified this kernel and all regressed (spill-like traffic
// signatures); the u16-V/unpack variant is retired. fp32 K + fp32 V staged
// in LDS (49.2 KB, 3 blocks/CU), weights inline, one barrier.
// ---------------------------------------------------------------------------
__global__ __launch_bounds__(256, 3) void attn_kernel(
    const float* __restrict__ Qf, const float* __restrict__ Kf, const u16* __restrict__ Vh,
    float* __restrict__ attn, float* __restrict__ xout)
{
    __shared__ alignas(16) float Ks[4][24][64];   // 24.6 KB
    __shared__ alignas(16) float Vs[4][24][64];   // 24.6 KB

    const int c2 = blockIdx.x, b = blockIdx.y, hg = blockIdx.z;
    const int t = threadIdx.x, lane = t & 63, w = t >> 6;   // w = head-in-group
    const int h = hg * 4 + w;
    const int qq = lane >> 2, ks = lane & 3;
    const int bh = b * 8 + h;
    const int lbase = c2 * 12 - 6;                 // staged row 0 -> global row lbase

    // --- stage K (fp32) + V (bf16->fp32) for 4 heads x 24 rows, zero-fill OOB ---
    for (int i = t; i < 1536; i += 256) {          // 1536 = 4 heads * 24 rows * 16 float4
        const int hh  = i / 384;
        const int rem = i - hh * 384;
        const int rr  = rem >> 4;
        const int cc  = (rem & 15) * 4;
        const int l = lbase + rr;
        float4 kf4 = make_float4(0.f, 0.f, 0.f, 0.f);
        float4 vf4 = make_float4(0.f, 0.f, 0.f, 0.f);
        if (l >= 0 && l < L_) {
            const size_t base = ((size_t)(b * 8 + hg * 4 + hh) * L_ + l) * 64 + cc;
            kf4 = *(const float4*)(Kf + base);
            const ushort4 u4 = *(const ushort4*)(Vh + base);
            vf4.x = bf2f(u4.x); vf4.y = bf2f(u4.y); vf4.z = bf2f(u4.z); vf4.w = bf2f(u4.w);
        }
        *(float4*)&Ks[hh][rr][cc] = kf4;
        *(float4*)&Vs[hh][rr][cc] = vf4;
    }
    __syncthreads();

    #pragma unroll
    for (int j = 0; j < 2; ++j) {
        const int c = c2 * 2 + j;
        const bool hasA = (c < NW), hasB = (c > 0);     // uniform per j-iteration
        const float scale = (hasA && hasB) ? 0.5f : 1.0f;
        const int koff = 6 * j;                          // staged-row offset of this chunk

        // Q segment for global row c*6+qq (zeros on invalid lanes -> s==0, finite)
        float4 qs0, qs1, qs2, qs3;
        const int qmax = hasA ? 12 : 6;
        if (qq < qmax) {
            const float* qp = Qf + ((size_t)bh * L_ + (c * 6 + qq)) * 64 + ks * 16;
            qs0 = *(const float4*)(qp);     qs1 = *(const float4*)(qp + 4);
            qs2 = *(const float4*)(qp + 8); qs3 = *(const float4*)(qp + 12);
        } else {
            qs0 = qs1 = qs2 = qs3 = make_float4(0.f, 0.f, 0.f, 0.f);
        }

        // --- unified dot pass vs the chunk's 18 staged K rows ---
        float s[18];
        #pragma unroll
        for (int kt = 0; kt < 18; ++kt) {
            const float* kp = &Ks[w][koff + kt][ks * 16];
            const float4 k0 = *(const float4*)(kp);
            const float4 k1 = *(const float4*)(kp + 4);
            const float4 k2 = *(const float4*)(kp + 8);
            const float4 k3 = *(const float4*)(kp + 12);
            s[kt] = qs0.x*k0.x + qs0.y*k0.y + qs0.z*k0.z + qs0.w*k0.w
                  + qs1.x*k1.x + qs1.y*k1.y + qs1.z*k1.z + qs1.w*k1.w
                  + qs2.x*k2.x + qs2.y*k2.y + qs2.z*k2.z + qs2.w*k2.w
                  + qs3.x*k3.x + qs3.y*k3.y + qs3.z*k3.z + qs3.w*k3.w;
        }
        #pragma unroll
        for (int kt = 0; kt < 18; ++kt) {
            s[kt] += __shfl_xor(s[kt], 1);
            s[kt] += __shfl_xor(s[kt], 2);
        }

        // --- softmax A: window c, over s[6..17] ---
        float eA[12], invA = 0.f;
        if (hasA) {
            float mxA = s[6];
            #pragma unroll
            for (int jj = 1; jj < 12; ++jj) mxA = fmaxf(mxA, s[6 + jj]);
            float sumA = 0.f;
            #pragma unroll
            for (int jj = 0; jj < 12; ++jj) { eA[jj] = __expf((s[6 + jj] - mxA) * 0.125f); sumA += eA[jj]; }
            invA = 1.0f / sumA;
            if (ks == 0 && qq < 12) {
                float* ao = attn + ((size_t)bh * NW + c) * 144 + qq * 12;
                float4 a0, a1, a2;
                a0.x = eA[0]*invA; a0.y = eA[1]*invA;  a0.z = eA[2]*invA;  a0.w = eA[3]*invA;
                a1.x = eA[4]*invA; a1.y = eA[5]*invA;  a1.z = eA[6]*invA;  a1.w = eA[7]*invA;
                a2.x = eA[8]*invA; a2.y = eA[9]*invA;  a2.z = eA[10]*invA; a2.w = eA[11]*invA;
                *(float4*)(ao)     = a0;
                *(float4*)(ao + 4) = a1;
                *(float4*)(ao + 8) = a2;
            }
        } else {
            #pragma unroll
            for (int jj = 0; jj < 12; ++jj) eA[jj] = 0.f;
        }

        // --- softmax B: window c-1 (this Q row acts as its row qq+6), s[0..11] ---
        float eB[12], invB = 0.f;
        if (hasB) {
            float mxB = s[0];
            #pragma unroll
            for (int jj = 1; jj < 12; ++jj) mxB = fmaxf(mxB, s[jj]);
            float sumB = 0.f;
            #pragma unroll
            for (int jj = 0; jj < 12; ++jj) { eB[jj] = __expf((s[jj] - mxB) * 0.125f); sumB += eB[jj]; }
            invB = 1.0f / sumB;
        } else {
            #pragma unroll
            for (int jj = 0; jj < 12; ++jj) eB[jj] = 0.f;
        }

        // --- fused PV over the chunk's 18 rows with combined overlap-add weights ---
        if (qq < 6) {
            float4 xo0 = make_float4(0.f,0.f,0.f,0.f), xo1 = xo0, xo2 = xo0, xo3 = xo0;
            #pragma unroll
            for (int kt = 0; kt < 18; ++kt) {
                const float wa = (kt >= 6) ? eA[kt - 6] * invA : 0.f;
                const float wb = (kt < 12) ? eB[kt] * invB : 0.f;
                const float wk = scale * (wa + wb);
                const float* vp = &Vs[w][koff + kt][ks * 16];
                const float4 v0 = *(const float4*)(vp);
                const float4 v1 = *(const float4*)(vp + 4);
                const float4 v2 = *(const float4*)(vp + 8);
                const float4 v3 = *(const float4*)(vp + 12);
                xo0.x += wk*v0.x; xo0.y += wk*v0.y; xo0.z += wk*v0.z; xo0.w += wk*v0.w;
                xo1.x += wk*v1.x; xo1.y += wk*v1.y; xo1.z += wk*v1.z; xo1.w += wk*v1.w;
                xo2.x += wk*v2.x; xo2.y += wk*v2.y; xo2.z += wk*v2.z; xo2.w += wk*v2.w;
                xo3.x += wk*v3.x; xo3.y += wk*v3.y; xo3.z += wk*v3.z; xo3.w += wk*v3.w;
            }
            float* xp = xout + ((size_t)b * L_ + (c * 6 + qq)) * DM + h * 64 + ks * 16;
            *(float4*)(xp)      = xo0;
            *(float4*)(xp + 4)  = xo1;
            *(float4*)(xp + 8)  = xo2;
            *(float4*)(xp + 12) = xo3;
        }
    }
}

// ---------------------------------------------------------------------------
// K2b: residual + LayerNorm, streaming (R6-proven). Wave = row. At its BW
// roofline (~100 MB r/w ~= 16 µs).
// ---------------------------------------------------------------------------
__global__ __launch_bounds__(512) void ln_kernel(
    const float* __restrict__ qres, const float* __restrict__ gamma,
    const float* __restrict__ beta, float* __restrict__ z)
{
    const int row = blockIdx.x * 8 + (threadIdx.x >> 6);   // 0..16367
    const int lane = threadIdx.x & 63;
    const int cc = lane * 8;

    float* xp = z + (size_t)row * DM + cc;
    float4 xa = *(const float4*)(xp);
    float4 xb = *(const float4*)(xp + 4);
    const float* qr = qres + (size_t)row * DM + cc;
    const float4 ra  = *(const float4*)qr;
    const float4 rb2 = *(const float4*)(qr + 4);
    xa.x += ra.x;  xa.y += ra.y;  xa.z += ra.z;  xa.w += ra.w;
    xb.x += rb2.x; xb.y += rb2.y; xb.z += rb2.z; xb.w += rb2.w;

    float s1 = xa.x + xa.y + xa.z + xa.w + xb.x + xb.y + xb.z + xb.w;
    float s2 = xa.x*xa.x + xa.y*xa.y + xa.z*xa.z + xa.w*xa.w
             + xb.x*xb.x + xb.y*xb.y + xb.z*xb.z + xb.w*xb.w;
    #pragma unroll
    for (int off = 1; off < 64; off <<= 1) {
        s1 += __shfl_xor(s1, off, 64);
        s2 += __shfl_xor(s2, off, 64);
    }
    const float mu  = s1 * (1.0f / 512.0f);
    const float var = s2 * (1.0f / 512.0f) - mu * mu;
    const float inv = 1.0f / sqrtf(var + EPS_);

    const float4 ga = *(const float4*)(gamma + cc);
    const float4 gb = *(const float4*)(gamma + cc + 4);
    const float4 ba = *(const float4*)(beta + cc);
    const float4 bb = *(const float4*)(beta + cc + 4);
    float4 oa, ob;
    oa.x = (xa.x - mu) * inv * ga.x + ba.x;
    oa.y = (xa.y - mu) * inv * ga.y + ba.y;
    oa.z = (xa.z - mu) * inv * ga.z + ba.z;
    oa.w = (xa.w - mu) * inv * ga.w + ba.w;
    ob.x = (xb.x - mu) * inv * gb.x + bb.x;
    ob.y = (xb.y - mu) * inv * gb.y + bb.y;
    ob.z = (xb.z - mu) * inv * gb.z + bb.z;
    ob.w = (xb.w - mu) * inv * gb.w + bb.w;
    *(float4*)(xp)     = oa;
    *(float4*)(xp + 4) = ob;
}

extern "C" void kernel_launch(void* const* d_in, const int* in_sizes, int n_in,
                              void* d_out, int out_size, void* d_ws, size_t ws_size,
                              hipStream_t stream) {
    const float* q     = (const float*)d_in[0];
    const float* k     = (const float*)d_in[1];
    const float* v     = (const float*)d_in[2];
    const float* Wq    = (const float*)d_in[3];
    const float* Wk    = (const float*)d_in[4];
    const float* Wv    = (const float*)d_in[5];
    const float* gamma = (const float*)d_in[6];
    const float* beta  = (const float*)d_in[7];

    float* z    = (float*)d_out;
    float* attn = (float*)d_out + Z_ELEMS;

    // Workspace: Qf fp32 (33.5 MB) + Kf fp32 (33.5 MB) + Vh bf16 (16.8 MB)
    const size_t plane = (size_t)B_ * H_ * L_ * 64;   // 8,380,416 elements
    float* Qf = (float*)d_ws;
    float* Kf = Qf + plane;
    u16*  Vh  = (u16*)(Kf + plane);

    proj_kernel<<<dim3(1024, 3, 1), 256, 0, stream>>>(q, k, v, Wq, Wk, Wv, Qf, Kf, Vh);
    attn_kernel<<<dim3(NC2, B_, 2), 256, 0, stream>>>(Qf, Kf, Vh, attn, z);
    ln_kernel<<<dim3(2046, 1, 1), 512, 0, stream>>>(q, gamma, beta, z);
}